// Round 8
// baseline (6448.167 us; speedup 1.0000x reference)
//
#include <hip/hip_runtime.h>
#include <math.h>

typedef float v2f __attribute__((ext_vector_type(2)));

#define EPSV 1e-5f
#define SBAR() __builtin_amdgcn_sched_barrier(0)

struct __align__(16) WS {
  float W1[128]; float b1[32]; float W2[128]; float b2[4];
  float G1[128]; float gb1[32]; float l1g[32]; float l1b[32];
  float G2[1024]; float gb2[32]; float l2g[32]; float l2b[32];
  float G3[128]; float gb3[4];
};

// packed a += s * {wx,wy} -> v_pk_fma_f32. v2f ONLY as named locals (R6 lesson).
__device__ __forceinline__ v2f pkfma(float s, float wx, float wy, v2f a) {
  v2f w = {wx, wy};
  v2f sv = {s, s};
  return __builtin_elementwise_fma(sv, w, a);
}

__device__ __forceinline__ float ftanh(float x) {
  // tanh(x) = 1 - 2/(exp(2x)+1). No clamp needed: exp->inf => rcp->0 => 1;
  // exp->0 => rcp(1)=1 => -1. Asymptotes exact.
  float e = __expf(x + x);
  float r = __builtin_amdgcn_rcpf(e + 1.0f);
  return fmaf(-2.0f, r, 1.0f);
}

// LayerNorm over 32 values held 16-per-lane across a lane pair.
__device__ __forceinline__ void lnorm16_pair(float* t, const float* g, const float* b) {
  float s = 0.f, ss = 0.f;
  #pragma unroll
  for (int i = 0; i < 16; ++i) { s += t[i]; ss = fmaf(t[i], t[i], ss); }
  s  += __shfl_xor(s, 1);
  ss += __shfl_xor(ss, 1);
  float m = s * 0.03125f;
  float v = fmaf(-m, m, ss * 0.03125f);
  float r = __frsqrt_rn(v + EPSV);
  #pragma unroll
  for (int i = 0; i < 16; ++i) t[i] = fmaf((t[i] - m) * r, g[i], b[i]);
}

// f-eval for TWO systems per lane-pair: lane p owns cols [16p,16p+16) of each
// 32-wide layer for BOTH systems. Every LDS weight read feeds both systems
// (halves LDS instr per system-eval -- the R7 bottleneck).
__device__ __forceinline__ void fode2(const WS* w, int p,
                                      const float yA[4], const float yB[4],
                                      float outA[4], float outB[4]) {
  const float4* W1v  = (const float4*)w->W1;
  const float4* b1v  = (const float4*)w->b1;
  const float4* W2v  = (const float4*)w->W2;
  const float4* G1v  = (const float4*)w->G1;
  const float4* gb1v = (const float4*)w->gb1;
  const float4* G2v  = (const float4*)w->G2;
  const float4* gb2v = (const float4*)w->gb2;
  const float4* G3v  = (const float4*)w->G3;
  const int j0 = p * 4;          // my float4 column-group base (of 8)
  const int r0 = p * 16;         // my row base (of 32)
  const int rp = r0 ^ 16;        // partner's row base

  // ---- magnitude net ----
  v2f mA0 = {0.f,0.f}, mA1 = {0.f,0.f}, mB0 = {0.f,0.f}, mB1 = {0.f,0.f};
  #pragma unroll
  for (int j = 0; j < 4; ++j) {
    float4 bb = b1v[j0 + j];
    v2f aA0 = {bb.x, bb.y}, aA1 = {bb.z, bb.w};
    v2f aB0 = {bb.x, bb.y}, aB1 = {bb.z, bb.w};
    #pragma unroll
    for (int i = 0; i < 4; ++i) {
      float4 wv = W1v[i * 8 + j0 + j];
      aA0 = pkfma(yA[i], wv.x, wv.y, aA0); aA1 = pkfma(yA[i], wv.z, wv.w, aA1);
      aB0 = pkfma(yB[i], wv.x, wv.y, aB0); aB1 = pkfma(yB[i], wv.z, wv.w, aB1);
    }
    float hA0 = ftanh(aA0.x), hA1 = ftanh(aA0.y), hA2 = ftanh(aA1.x), hA3 = ftanh(aA1.y);
    float hB0 = ftanh(aB0.x), hB1 = ftanh(aB0.y), hB2 = ftanh(aB1.x), hB3 = ftanh(aB1.y);
    float4 w0 = W2v[r0 + 4*j + 0];
    mA0 = pkfma(hA0, w0.x, w0.y, mA0); mA1 = pkfma(hA0, w0.z, w0.w, mA1);
    mB0 = pkfma(hB0, w0.x, w0.y, mB0); mB1 = pkfma(hB0, w0.z, w0.w, mB1);
    float4 w1 = W2v[r0 + 4*j + 1];
    mA0 = pkfma(hA1, w1.x, w1.y, mA0); mA1 = pkfma(hA1, w1.z, w1.w, mA1);
    mB0 = pkfma(hB1, w1.x, w1.y, mB0); mB1 = pkfma(hB1, w1.z, w1.w, mB1);
    float4 w2 = W2v[r0 + 4*j + 2];
    mA0 = pkfma(hA2, w2.x, w2.y, mA0); mA1 = pkfma(hA2, w2.z, w2.w, mA1);
    mB0 = pkfma(hB2, w2.x, w2.y, mB0); mB1 = pkfma(hB2, w2.z, w2.w, mB1);
    float4 w3 = W2v[r0 + 4*j + 3];
    mA0 = pkfma(hA3, w3.x, w3.y, mA0); mA1 = pkfma(hA3, w3.z, w3.w, mA1);
    mB0 = pkfma(hB3, w3.x, w3.y, mB0); mB1 = pkfma(hB3, w3.z, w3.w, mB1);
    SBAR();
  }

  // ---- gating layer 1 ----
  float tmA[16], tmB[16];
  #pragma unroll
  for (int j = 0; j < 4; ++j) {
    float4 bb = gb1v[j0 + j];
    v2f aA0 = {bb.x, bb.y}, aA1 = {bb.z, bb.w};
    v2f aB0 = {bb.x, bb.y}, aB1 = {bb.z, bb.w};
    #pragma unroll
    for (int i = 0; i < 4; ++i) {
      float4 wv = G1v[i * 8 + j0 + j];
      aA0 = pkfma(yA[i], wv.x, wv.y, aA0); aA1 = pkfma(yA[i], wv.z, wv.w, aA1);
      aB0 = pkfma(yB[i], wv.x, wv.y, aB0); aB1 = pkfma(yB[i], wv.z, wv.w, aB1);
    }
    tmA[4*j+0] = ftanh(aA0.x); tmA[4*j+1] = ftanh(aA0.y);
    tmA[4*j+2] = ftanh(aA1.x); tmA[4*j+3] = ftanh(aA1.y);
    tmB[4*j+0] = ftanh(aB0.x); tmB[4*j+1] = ftanh(aB0.y);
    tmB[4*j+2] = ftanh(aB1.x); tmB[4*j+3] = ftanh(aB1.y);
    SBAR();
  }
  lnorm16_pair(tmA, w->l1g + r0, w->l1b + r0);
  lnorm16_pair(tmB, w->l1g + r0, w->l1b + r0);

  // ---- exchange: partner half via shfl (no reorder/select needed:
  // dot-product order is commutative; partner rows addressed via rp) ----
  float ptA[16], ptB[16];
  #pragma unroll
  for (int i = 0; i < 16; ++i) {
    ptA[i] = __shfl_xor(tmA[i], 1);
    ptB[i] = __shfl_xor(tmB[i], 1);
  }
  SBAR();

  // ---- gating layer 2 ----
  float umA[16], umB[16];
  #pragma unroll
  for (int j = 0; j < 4; ++j) {
    float4 bb = gb2v[j0 + j];
    v2f aA0 = {bb.x, bb.y}, aA1 = {bb.z, bb.w};
    v2f aB0 = {bb.x, bb.y}, aB1 = {bb.z, bb.w};
    #pragma unroll
    for (int i = 0; i < 16; ++i) {
      float4 wm = G2v[(r0 + i) * 8 + j0 + j];   // my rows, my tm
      aA0 = pkfma(tmA[i], wm.x, wm.y, aA0); aA1 = pkfma(tmA[i], wm.z, wm.w, aA1);
      aB0 = pkfma(tmB[i], wm.x, wm.y, aB0); aB1 = pkfma(tmB[i], wm.z, wm.w, aB1);
      float4 wp = G2v[(rp + i) * 8 + j0 + j];   // partner rows, partner t
      aA0 = pkfma(ptA[i], wp.x, wp.y, aA0); aA1 = pkfma(ptA[i], wp.z, wp.w, aA1);
      aB0 = pkfma(ptB[i], wp.x, wp.y, aB0); aB1 = pkfma(ptB[i], wp.z, wp.w, aB1);
      if (i == 5 || i == 10) SBAR();
    }
    umA[4*j+0] = ftanh(aA0.x); umA[4*j+1] = ftanh(aA0.y);
    umA[4*j+2] = ftanh(aA1.x); umA[4*j+3] = ftanh(aA1.y);
    umB[4*j+0] = ftanh(aB0.x); umB[4*j+1] = ftanh(aB0.y);
    umB[4*j+2] = ftanh(aB1.x); umB[4*j+3] = ftanh(aB1.y);
    SBAR();
  }
  lnorm16_pair(umA, w->l2g + r0, w->l2b + r0);
  lnorm16_pair(umB, w->l2g + r0, w->l2b + r0);

  // ---- G3 partials over my 16 rows, then pair-reduce ----
  v2f zA0 = {0.f,0.f}, zA1 = {0.f,0.f}, zB0 = {0.f,0.f}, zB1 = {0.f,0.f};
  #pragma unroll
  for (int i = 0; i < 16; ++i) {
    float4 wv = G3v[r0 + i];
    zA0 = pkfma(umA[i], wv.x, wv.y, zA0); zA1 = pkfma(umA[i], wv.z, wv.w, zA1);
    zB0 = pkfma(umB[i], wv.x, wv.y, zB0); zB1 = pkfma(umB[i], wv.z, wv.w, zB1);
    if (i == 7) SBAR();
  }
  SBAR();

  float4 b2v  = *(const float4*)w->b2;
  float4 gb3v = *(const float4*)w->gb3;
  {
    float zx = zA0.x + __shfl_xor(zA0.x, 1) + gb3v.x;
    float zy = zA0.y + __shfl_xor(zA0.y, 1) + gb3v.y;
    float zz = zA1.x + __shfl_xor(zA1.x, 1) + gb3v.z;
    float zw = zA1.y + __shfl_xor(zA1.y, 1) + gb3v.w;
    float mx = mA0.x + __shfl_xor(mA0.x, 1) + b2v.x;
    float my = mA0.y + __shfl_xor(mA0.y, 1) + b2v.y;
    float mz = mA1.x + __shfl_xor(mA1.x, 1) + b2v.z;
    float mw = mA1.y + __shfl_xor(mA1.y, 1) + b2v.w;
    outA[0] = mx * __expf(-zx * zx);
    outA[1] = my * __expf(-zy * zy);
    outA[2] = mz * __expf(-zz * zz);
    outA[3] = mw * __expf(-zw * zw);
  }
  {
    float zx = zB0.x + __shfl_xor(zB0.x, 1) + gb3v.x;
    float zy = zB0.y + __shfl_xor(zB0.y, 1) + gb3v.y;
    float zz = zB1.x + __shfl_xor(zB1.x, 1) + gb3v.z;
    float zw = zB1.y + __shfl_xor(zB1.y, 1) + gb3v.w;
    float mx = mB0.x + __shfl_xor(mB0.x, 1) + b2v.x;
    float my = mB0.y + __shfl_xor(mB0.y, 1) + b2v.y;
    float mz = mB1.x + __shfl_xor(mB1.x, 1) + b2v.z;
    float mw = mB1.y + __shfl_xor(mB1.y, 1) + b2v.w;
    outB[0] = mx * __expf(-zx * zx);
    outB[1] = my * __expf(-zy * zy);
    outB[2] = mz * __expf(-zz * zz);
    outB[3] = mw * __expf(-zw * zw);
  }
}

__global__ __launch_bounds__(256, 1) void ode_kernel(
    const float* __restrict__ s_grid, const float* __restrict__ y0,
    const float* __restrict__ W1, const float* __restrict__ b1,
    const float* __restrict__ W2, const float* __restrict__ b2,
    const float* __restrict__ G1, const float* __restrict__ gb1,
    const float* __restrict__ l1g, const float* __restrict__ l1b,
    const float* __restrict__ G2, const float* __restrict__ gb2,
    const float* __restrict__ l2g, const float* __restrict__ l2b,
    const float* __restrict__ G3, const float* __restrict__ gb3,
    float* __restrict__ out, int T, int B) {
  __shared__ WS w;
  __shared__ float sg[512];
  const int tx = threadIdx.x;

  for (int i = tx; i < 128; i += 256) {
    w.W1[i] = W1[i]; w.W2[i] = W2[i]; w.G1[i] = G1[i]; w.G3[i] = G3[i];
  }
  for (int i = tx; i < 1024; i += 256) w.G2[i] = G2[i];
  if (tx < 32) {
    w.b1[tx] = b1[tx]; w.gb1[tx] = gb1[tx];
    w.l1g[tx] = l1g[tx]; w.l1b[tx] = l1b[tx];
    w.gb2[tx] = gb2[tx];
    w.l2g[tx] = l2g[tx]; w.l2b[tx] = l2b[tx];
  }
  if (tx < 4) { w.b2[tx] = b2[tx]; w.gb3[tx] = gb3[tx]; }
  for (int i = tx; i < T && i < 512; i += 256) sg[i] = s_grid[i];
  __syncthreads();

  // lane-pair (2q,2q+1) handles systems sA=2q and sB=2q+1; lane p owns
  // cols [16p,16p+16) of both. Store index: t*B + 2q + p = t*B + tid.
  const int tid = blockIdx.x * 256 + tx;
  const int p  = tid & 1;
  const bool pb = (p != 0);
  const int sA = tid & ~1;
  const int sB = sA + 1;
  if (sB >= B + 1) return;  // B is even in this problem

  float4 yA0 = ((const float4*)y0)[sA];
  float4 yB0 = ((const float4*)y0)[sB];
  float yA[4] = {yA0.x, yA0.y, yA0.z, yA0.w};
  float yB[4] = {yB0.x, yB0.y, yB0.z, yB0.w};
  ((float4*)out)[tid] = pb ? yB0 : yA0;  // t = 0 row

  #pragma unroll 1
  for (int t = 0; t < T - 1; ++t) {
    const float h = sg[t + 1] - sg[t];
    float kA[4], kB[4], ksA[4], ksB[4], ytA[4], ytB[4];

    fode2(&w, p, yA, yB, kA, kB);
    #pragma unroll
    for (int c = 0; c < 4; ++c) {
      ksA[c] = kA[c]; ytA[c] = fmaf(0.5f * h, kA[c], yA[c]);
      ksB[c] = kB[c]; ytB[c] = fmaf(0.5f * h, kB[c], yB[c]);
    }
    SBAR();
    fode2(&w, p, ytA, ytB, kA, kB);
    #pragma unroll
    for (int c = 0; c < 4; ++c) {
      ksA[c] = fmaf(2.0f, kA[c], ksA[c]); ytA[c] = fmaf(0.5f * h, kA[c], yA[c]);
      ksB[c] = fmaf(2.0f, kB[c], ksB[c]); ytB[c] = fmaf(0.5f * h, kB[c], yB[c]);
    }
    SBAR();
    fode2(&w, p, ytA, ytB, kA, kB);
    #pragma unroll
    for (int c = 0; c < 4; ++c) {
      ksA[c] = fmaf(2.0f, kA[c], ksA[c]); ytA[c] = fmaf(h, kA[c], yA[c]);
      ksB[c] = fmaf(2.0f, kB[c], ksB[c]); ytB[c] = fmaf(h, kB[c], yB[c]);
    }
    SBAR();
    fode2(&w, p, ytA, ytB, kA, kB);
    #pragma unroll
    for (int c = 0; c < 4; ++c) {
      yA[c] = fmaf(h * (1.0f / 6.0f), ksA[c] + kA[c], yA[c]);
      yB[c] = fmaf(h * (1.0f / 6.0f), ksB[c] + kB[c], yB[c]);
    }

    float4 yo;
    yo.x = pb ? yB[0] : yA[0];
    yo.y = pb ? yB[1] : yA[1];
    yo.z = pb ? yB[2] : yA[2];
    yo.w = pb ? yB[3] : yA[3];
    ((float4*)out)[(size_t)(t + 1) * B + tid] = yo;
  }
}

extern "C" void kernel_launch(void* const* d_in, const int* in_sizes, int n_in,
                              void* d_out, int out_size, void* d_ws, size_t ws_size,
                              hipStream_t stream) {
  const float* s_grid = (const float*)d_in[0];
  const float* y0     = (const float*)d_in[1];
  const float* W1     = (const float*)d_in[2];
  const float* b1     = (const float*)d_in[3];
  const float* W2     = (const float*)d_in[4];
  const float* b2     = (const float*)d_in[5];
  const float* G1     = (const float*)d_in[6];
  const float* gb1    = (const float*)d_in[7];
  const float* l1g    = (const float*)d_in[8];
  const float* l1b    = (const float*)d_in[9];
  const float* G2     = (const float*)d_in[10];
  const float* gb2    = (const float*)d_in[11];
  const float* l2g    = (const float*)d_in[12];
  const float* l2b    = (const float*)d_in[13];
  const float* G3     = (const float*)d_in[14];
  const float* gb3    = (const float*)d_in[15];

  const int T = in_sizes[0];
  const int B = in_sizes[1] / 4;

  const int threads = B;  // one lane per system; lane-pair shares weight reads
  dim3 block(256);
  dim3 grid((threads + 255) / 256);
  hipLaunchKernelGGL(ode_kernel, grid, block, 0, stream,
                     s_grid, y0, W1, b1, W2, b2, G1, gb1, l1g, l1b,
                     G2, gb2, l2g, l2b, G3, gb3, (float*)d_out, T, B);
}